// Round 8
// baseline (315.273 us; speedup 1.0000x reference)
//
#include <hip/hip_runtime.h>

// ---------------------------------------------------------------------------
// WaveSubsystem fused:
//   out = tanh(c@W_mod + b_mod) * (a_diag*w + (w@AV)@AU^T) + [c z]@W_B + b_B
// Round 14: LOW-RANK path replaces the dense Mt. Prep blocks 0..127 compute
// t = w@AV (fp32 inputs, BK=32 Mt-builder pattern; AV's [K][N] layout handled
// by a per-iter LDS bounce: coalesced load -> bf16 -> transposed gather).
// These blocks depend on NOTHING from the conversion blocks -> they overlap
// the BW-bound conversions. fused phase B becomes t@AU^T with K=512 (4 ksteps
// instead of 16; AU consumed as-is, [n][k] row-major) + diag term folded into
// the mod multiply. Total fused ksteps 48 -> 36 (-25%). Mt fully removed.
// fused structure otherwise byte-identical to r13 (proven 109 us, XCD swizzle
// kept: FETCH 214->133 MB measured).
// ---------------------------------------------------------------------------

#define DEV __device__ __forceinline__

typedef __bf16 v8bf __attribute__((ext_vector_type(8)));
typedef __bf16 v4bf __attribute__((ext_vector_type(4)));
typedef float  v4f  __attribute__((ext_vector_type(4)));

typedef __attribute__((address_space(1))) const unsigned int* as1_cuint_ptr;
typedef __attribute__((address_space(3))) unsigned int*       as3_uint_ptr;

DEV void async16(const void* g, void* l) {
  __builtin_amdgcn_global_load_lds(
      (as1_cuint_ptr)(unsigned long long)g,
      (as3_uint_ptr)(unsigned long long)l,
      16, 0, 0);
}

DEV float tanh_fast(float x) {
  x = fminf(15.f, fmaxf(-15.f, x));
  float e = __expf(2.f * x);
  return (e - 1.f) / (e + 1.f);
}

// ----------------------- merged prep + t-GEMM kernel -----------------------
// blocks [0,128):       t = w@AV  (fp32 in, [4096][512] bf16 out) -- no
//                       dependency on conversion blocks, overlaps them
// blocks [128,2176):    grid-stride fp32->bf16 convert of w,z,c,AU (21504 u)
// blocks [2176,3200):   grid-stride transpose+convert Wmod,WB (8192 units)
__global__ __launch_bounds__(256, 2) void prep_gemm(
    const float* __restrict__ w, const float* __restrict__ z,
    const float* __restrict__ c, const float* __restrict__ au,
    const float* __restrict__ av, const float* __restrict__ Wmod,
    const float* __restrict__ WB,
    __bf16* __restrict__ wb, __bf16* __restrict__ zb, __bf16* __restrict__ cb,
    __bf16* __restrict__ AUb, __bf16* __restrict__ Wmodt,
    __bf16* __restrict__ WBt, __bf16* __restrict__ tb) {
  __shared__ __align__(16) char smem[25600];
  int b = blockIdx.x;

  if (b < 128) {
    // ---- t = w @ AV: 128x128 tile, K=2048, BK=32 ----
    // grid 32 m-tiles x 4 n-tiles (rank = 512)
    __bf16* As   = (__bf16*)smem;             // [128][32] bf16, 8 KB
    __bf16* Bs   = (__bf16*)(smem + 8192);    // [128][32] bf16, 8 KB
    __bf16* Braw = (__bf16*)(smem + 16384);   // [32][130] bf16, 8.3 KB
    const int tid = threadIdx.x, lane = tid & 63, wid = tid >> 6;
    const int wm = wid >> 1, wn = wid & 1, l16 = lane & 15, quad = lane >> 4;
    const int m0 = (b >> 2) * 128, n0 = (b & 3) * 128;
    const int qs = quad ^ ((l16 >> 1) & 3);
    const int row = tid >> 1, sp = (tid & 1) * 2;
    const int kk = tid >> 3, nn = (tid & 7) * 16;  // Braw load geometry

    v4f acc[4][4];
#pragma unroll
    for (int i = 0; i < 4; ++i)
#pragma unroll
      for (int j = 0; j < 4; ++j) { v4f zz = {0, 0, 0, 0}; acc[i][j] = zz; }

    for (int k0 = 0; k0 < 2048; k0 += 32) {
      __syncthreads();
      // A: w fp32 -> bf16 -> As, slot-swizzled (LDS slot s of row r holds
      // global k-group s^((r>>1)&3))
#pragma unroll
      for (int ss = 0; ss < 2; ++ss) {
        const int s = sp + ss;
        const int gk = (s ^ ((row >> 1) & 3)) * 8;
        const float* pa = w + (size_t)(m0 + row) * 2048 + k0 + gk;
        float4 a0 = *reinterpret_cast<const float4*>(pa);
        float4 a1 = *reinterpret_cast<const float4*>(pa + 4);
        v8bf va;
        va[0] = (__bf16)a0.x; va[1] = (__bf16)a0.y;
        va[2] = (__bf16)a0.z; va[3] = (__bf16)a0.w;
        va[4] = (__bf16)a1.x; va[5] = (__bf16)a1.y;
        va[6] = (__bf16)a1.z; va[7] = (__bf16)a1.w;
        *reinterpret_cast<v8bf*>(&As[row * 32 + s * 8]) = va;
      }
      // Braw: AV[k0+kk][n0+nn .. nn+15] -> bf16, row-major [k][130]
      {
        const float* pb = av + (size_t)(k0 + kk) * 512 + n0 + nn;
        float4 b0 = *reinterpret_cast<const float4*>(pb);
        float4 b1 = *reinterpret_cast<const float4*>(pb + 4);
        float4 b2 = *reinterpret_cast<const float4*>(pb + 8);
        float4 b3 = *reinterpret_cast<const float4*>(pb + 12);
        v8bf v0, v1;
        v0[0] = (__bf16)b0.x; v0[1] = (__bf16)b0.y;
        v0[2] = (__bf16)b0.z; v0[3] = (__bf16)b0.w;
        v0[4] = (__bf16)b1.x; v0[5] = (__bf16)b1.y;
        v0[6] = (__bf16)b1.z; v0[7] = (__bf16)b1.w;
        v1[0] = (__bf16)b2.x; v1[1] = (__bf16)b2.y;
        v1[2] = (__bf16)b2.z; v1[3] = (__bf16)b2.w;
        v1[4] = (__bf16)b3.x; v1[5] = (__bf16)b3.y;
        v1[6] = (__bf16)b3.z; v1[7] = (__bf16)b3.w;
        *reinterpret_cast<v8bf*>(&Braw[kk * 130 + nn]) = v0;
        *reinterpret_cast<v8bf*>(&Braw[kk * 130 + nn + 8]) = v1;
      }
      __syncthreads();
      // stage-2: transposed gather. LDS slot s of n-row must hold global
      // k-group s^((row>>1)&3) -> gather that group's 8 k-elems at col row.
#pragma unroll
      for (int ss = 0; ss < 2; ++ss) {
        const int s = sp + ss;
        const int sg = s ^ ((row >> 1) & 3);
        v8bf vb;
#pragma unroll
        for (int e = 0; e < 8; ++e) vb[e] = Braw[(sg * 8 + e) * 130 + row];
        *reinterpret_cast<v8bf*>(&Bs[row * 32 + s * 8]) = vb;
      }
      __syncthreads();
      const v8bf* Ap = reinterpret_cast<const v8bf*>(As);
      const v8bf* Bp = reinterpret_cast<const v8bf*>(Bs);
      v8bf a[4], bb[4];
#pragma unroll
      for (int i = 0; i < 4; ++i) a[i] = Ap[(wm * 64 + i * 16 + l16) * 4 + qs];
#pragma unroll
      for (int j = 0; j < 4; ++j) bb[j] = Bp[(wn * 64 + j * 16 + l16) * 4 + qs];
#pragma unroll
      for (int i = 0; i < 4; ++i)
#pragma unroll
        for (int j = 0; j < 4; ++j)
          acc[i][j] = __builtin_amdgcn_mfma_f32_16x16x32_bf16(a[i], bb[j],
                                                              acc[i][j], 0, 0, 0);
    }

    const int mBase = m0 + wm * 64 + quad * 4;
    const int nBase = n0 + wn * 64 + l16;
#pragma unroll
    for (int j = 0; j < 4; ++j) {
      const int n = nBase + j * 16;
#pragma unroll
      for (int i = 0; i < 4; ++i)
#pragma unroll
        for (int r = 0; r < 4; ++r)
          tb[(size_t)(mBase + i * 16 + r) * 512 + n] = (__bf16)acc[i][j][r];
    }
    return;
  }

  b -= 128;
  if (b < 2048) {
    // ---- fp32 -> bf16 conversion, grid-stride over 21504 units ----
    // w: 8192, z: 8192, c: 4096, AU: 1024
    for (int u = b; u < 21504; u += 2048) {
      const float* src; __bf16* dst; int off;
      if (u < 8192)       { src = w;  dst = wb;  off = u; }
      else if (u < 16384) { src = z;  dst = zb;  off = u - 8192; }
      else if (u < 20480) { src = c;  dst = cb;  off = u - 16384; }
      else                { src = au; dst = AUb; off = u - 20480; }
      size_t i = (size_t)off * 1024 + (size_t)threadIdx.x * 4;
      float4 v = *reinterpret_cast<const float4*>(src + i);
      v4bf o;
      o.x = (__bf16)v.x; o.y = (__bf16)v.y;
      o.z = (__bf16)v.z; o.w = (__bf16)v.w;
      *reinterpret_cast<v4bf*>(dst + i) = o;
    }
    return;
  }

  b -= 2048;
  // ---- transpose + convert: Wmod -> Wmodt, WB -> WBt (grid-stride) ----
  float (*t)[33] = (float(*)[33])smem;  // 32x33 fp32
  const int tx = threadIdx.x & 31, ty = threadIdx.x >> 5;
  const int orow = threadIdx.x >> 3;       // 0..31 output row within tile
  const int oc   = (threadIdx.x & 7) * 4;  // 0..28 output col group
  for (int u = b; u < 8192; u += 1024) {
    const float* src; __bf16* dst; int R, uu = u;
    if (uu < 2048) { src = Wmod; dst = Wmodt; R = 1024; }
    else           { uu -= 2048; src = WB; dst = WBt; R = 3072; }
    const int c0 = (uu & 63) * 32, r0 = (uu >> 6) * 32;
    const int C = 2048;
    __syncthreads();  // previous iteration's reads of t[] complete
#pragma unroll
    for (int rr = 0; rr < 32; rr += 8)
      t[ty + rr][tx] = src[(size_t)(r0 + ty + rr) * C + c0 + tx];
    __syncthreads();
    v4bf o;
    o.x = (__bf16)t[oc + 0][orow];
    o.y = (__bf16)t[oc + 1][orow];
    o.z = (__bf16)t[oc + 2][orow];
    o.w = (__bf16)t[oc + 3][orow];
    *reinterpret_cast<v4bf*>(&dst[(size_t)(c0 + orow) * R + r0 + oc]) = o;
  }
}

// ---------------------- fused main kernel ----------------------------------
// Proven r13 structure: 128x128 tile, 4 waves, BK=128 macro-steps, 64 KB LDS,
// 2 blocks/CU, XCD block swizzle. Phase B is now t@AU^T (K=512, 4 ksteps)
// with the diag term a_diag*w folded into the mod multiply.
__global__ __launch_bounds__(256, 2) void fused_main(
    const __bf16* __restrict__ c, const __bf16* __restrict__ z,
    const __bf16* __restrict__ w, const __bf16* __restrict__ Wmodt,
    const __bf16* __restrict__ tb, const __bf16* __restrict__ AUb,
    const __bf16* __restrict__ WBt, const float* __restrict__ A_diag,
    const float* __restrict__ b_mod, const float* __restrict__ b_B,
    float* __restrict__ out) {
  constexpr int DC = 1024, DW = 2048, KB = 3072, RK = 512;
  __shared__ __align__(16) __bf16 As[128 * 128];  // 32 KB
  __shared__ __align__(16) __bf16 Bs[128 * 128];  // 32 KB

  const int tid = threadIdx.x, lane = tid & 63, wid = tid >> 6;
  const int wm = wid >> 1, wn = wid & 1, l16 = lane & 15, quad = lane >> 4;
  // XCD-aware bijective remap (512 = 8 XCDs x 64): FETCH 214->133 MB (r13).
  const int flat = blockIdx.y * 16 + blockIdx.x;
  const int swz = (flat & 7) * 64 + (flat >> 3);
  const int m0 = (swz >> 4) * 128;  // batch
  const int n0 = (swz & 15) * 128;  // d_w
  const int r4  = lane >> 4;   // 0..3 row-within-instr
  const int s16 = lane & 15;   // LDS slot index

  v4f acc[4][4];
#pragma unroll
  for (int i = 0; i < 4; ++i)
#pragma unroll
    for (int j = 0; j < 4; ++j) { v4f zz = {0,0,0,0}; acc[i][j] = zz; }

  auto kstep = [&](const __bf16* gA, size_t lda, const __bf16* gB, size_t ldb,
                   int kA, int kB) {
    __syncthreads();
#pragma unroll
    for (int t = 0; t < 8; ++t) {
      const int row = wid * 32 + t * 4 + r4;
      const int gk = (s16 ^ (row & 15)) * 8;  // global k elem offset
      async16((const void*)(gA + (size_t)(m0 + row) * lda + kA + gk),
              (void*)&As[row * 128 + s16 * 8]);
      async16((const void*)(gB + (size_t)(n0 + row) * ldb + kB + gk),
              (void*)&Bs[row * 128 + s16 * 8]);
    }
    __syncthreads();
    const v8bf* Ap = reinterpret_cast<const v8bf*>(As);
    const v8bf* Bp = reinterpret_cast<const v8bf*>(Bs);
#pragma unroll
    for (int s = 0; s < 4; ++s) {
      const int rs = (s * 4 + quad) ^ l16;  // swizzled read slot
      v8bf a[4], b[4];
#pragma unroll
      for (int i = 0; i < 4; ++i)
        a[i] = Ap[(wm * 64 + i * 16 + l16) * 16 + rs];
#pragma unroll
      for (int j = 0; j < 4; ++j)
        b[j] = Bp[(wn * 64 + j * 16 + l16) * 16 + rs];
#pragma unroll
      for (int i = 0; i < 4; ++i)
#pragma unroll
        for (int j = 0; j < 4; ++j)
          acc[i][j] = __builtin_amdgcn_mfma_f32_16x16x32_bf16(
              a[i], b[j], acc[i][j], 0, 0, 0);
    }
  };

  const int nBase = n0 + wn * 64 + l16;
  const int mBase = m0 + wm * 64 + quad * 4;

  // ---- phase A: mod = tanh(c @ Wmodt + b_mod) ----
  for (int k0 = 0; k0 < DC; k0 += 128) kstep(c, DC, Wmodt, DC, k0, k0);

  v4f mod_s[4][4];
#pragma unroll
  for (int j = 0; j < 4; ++j) {
    const float bn = b_mod[nBase + j * 16];
#pragma unroll
    for (int i = 0; i < 4; ++i) {
#pragma unroll
      for (int r = 0; r < 4; ++r)
        mod_s[i][j][r] = tanh_fast(acc[i][j][r] + bn);
      v4f zz = {0,0,0,0};
      acc[i][j] = zz;
    }
  }

  // ---- phase B: acc = t @ AU^T  (K = rank = 512, 4 ksteps) ----
  for (int k0 = 0; k0 < RK; k0 += 128) kstep(tb, RK, AUb, RK, k0, k0);

  // ---- Aw = acc + a_diag*w; acc = mod * Aw ----
  {
    float adr[4];
#pragma unroll
    for (int j = 0; j < 4; ++j)
      adr[j] = tanh_fast(A_diag[nBase + j * 16]) * 0.9f;
#pragma unroll
    for (int i = 0; i < 4; ++i)
#pragma unroll
      for (int j = 0; j < 4; ++j)
#pragma unroll
        for (int r = 0; r < 4; ++r) {
          const float wv =
              (float)w[(size_t)(mBase + i * 16 + r) * DW + nBase + j * 16];
          acc[i][j][r] = (acc[i][j][r] + adr[j] * wv) * mod_s[i][j][r];
        }
  }

  // ---- phase C: acc += [c z] @ WBt ----
  for (int k0 = 0; k0 < DC; k0 += 128) kstep(c, DC, WBt, KB, k0, k0);
  for (int k0 = DC; k0 < KB; k0 += 128) kstep(z, DW, WBt, KB, k0 - DC, k0);

  // ---- epilogue ----
#pragma unroll
  for (int j = 0; j < 4; ++j) {
    const int n = nBase + j * 16;
    const float bn = b_B[n];
#pragma unroll
    for (int i = 0; i < 4; ++i)
#pragma unroll
      for (int r = 0; r < 4; ++r) {
        const int m = mBase + i * 16 + r;
        out[(size_t)m * DW + n] = acc[i][j][r] + bn;
      }
  }
}

// ------------------------------ launch -------------------------------------

extern "C" void kernel_launch(void* const* d_in, const int* in_sizes, int n_in,
                              void* d_out, int out_size, void* d_ws,
                              size_t ws_size, hipStream_t stream) {
  const float* w_prev = (const float*)d_in[0];
  const float* z_t    = (const float*)d_in[1];
  const float* c_t    = (const float*)d_in[2];
  const float* A_diag = (const float*)d_in[3];
  const float* A_U    = (const float*)d_in[4];
  const float* A_V    = (const float*)d_in[5];
  const float* W_mod  = (const float*)d_in[6];
  const float* b_mod  = (const float*)d_in[7];
  const float* W_B    = (const float*)d_in[8];
  const float* b_B    = (const float*)d_in[9];

  constexpr int Bsz = 4096, DW = 2048;
  const size_t MB = 1ull << 20;
  char* ws = (char*)d_ws;
  __bf16* w_bf  = (__bf16*)(ws + 0);        // 16 MB
  __bf16* z_bf  = (__bf16*)(ws + 16 * MB);  // 16 MB
  __bf16* c_bf  = (__bf16*)(ws + 32 * MB);  //  8 MB
  __bf16* Wmodt = (__bf16*)(ws + 40 * MB);  //  4 MB  [2048][1024]
  __bf16* WBt   = (__bf16*)(ws + 44 * MB);  // 12 MB  [2048][3072]
  __bf16* AUb   = (__bf16*)(ws + 56 * MB);  //  2 MB  [2048][512]
  __bf16* t_bf  = (__bf16*)(ws + 58 * MB);  //  4 MB  [4096][512]

  prep_gemm<<<3200, 256, 0, stream>>>(w_prev, z_t, c_t, A_U, A_V, W_mod, W_B,
                                      w_bf, z_bf, c_bf, AUb, Wmodt, WBt,
                                      t_bf);

  fused_main<<<dim3(DW / 128, Bsz / 128), 256, 0, stream>>>(
      c_bf, z_bf, w_bf, Wmodt, t_bf, AUb, WBt, A_diag, b_mod, b_B,
      (float*)d_out);
}